// Round 1
// baseline (1426.552 us; speedup 1.0000x reference)
//
#include <hip/hip_runtime.h>

// Problem constants (B,C,H,W = 8,256,64,64; inter = C/8 = 32; N = H*W = 4096)
#define BB 8
#define CC 256
#define NNX 4096
#define II 32

// Attention tiling
#define MT 64    // queries per block
#define NT 32    // key/value tile
#define KSTR 36  // K LDS row stride (16B-aligned rows, bank-spread)
#define VSTR 260 // V LDS row stride (16B-aligned rows, bank-spread)

// ---------------------------------------------------------------------------
// q/k projection: out[b,i,n] = sum_c W[i,c] * x[b,c,n] + bias[i], i < 32
// grid (N/256, B, 2): z=0 -> q, z=1 -> k. 256 threads, thread owns one n.
// ---------------------------------------------------------------------------
__global__ __launch_bounds__(256) void qk_proj(
    const float* __restrict__ x,
    const float* __restrict__ Wq, const float* __restrict__ bq,
    const float* __restrict__ Wk, const float* __restrict__ bk,
    float* __restrict__ q, float* __restrict__ k) {
  const int n = blockIdx.x * 256 + threadIdx.x;
  const int b = blockIdx.y;
  const float* W    = blockIdx.z ? Wk : Wq;
  const float* bias = blockIdx.z ? bk : bq;
  float* out        = blockIdx.z ? k  : q;

  const float* xb = x + (size_t)b * CC * NNX;
  float acc[II];
#pragma unroll
  for (int i = 0; i < II; ++i) acc[i] = 0.f;

  for (int c = 0; c < CC; ++c) {
    float xv = xb[(size_t)c * NNX + n];
#pragma unroll
    for (int i = 0; i < II; ++i) acc[i] += W[i * CC + c] * xv;
  }

  float* ob = out + (size_t)b * II * NNX;
#pragma unroll
  for (int i = 0; i < II; ++i) ob[(size_t)i * NNX + n] = acc[i] + bias[i];
}

// ---------------------------------------------------------------------------
// v projection: v[b,o,n] = sum_c Wv[o,c] * x[b,c,n] + bv[o]
// grid (N/256, B, 8): z picks a group of 32 output channels.
// ---------------------------------------------------------------------------
__global__ __launch_bounds__(256) void v_proj(
    const float* __restrict__ x,
    const float* __restrict__ Wv, const float* __restrict__ bv,
    float* __restrict__ v) {
  const int n  = blockIdx.x * 256 + threadIdx.x;
  const int b  = blockIdx.y;
  const int og = blockIdx.z;  // output-channel group of 32

  const float* xb = x + (size_t)b * CC * NNX;
  float acc[32];
#pragma unroll
  for (int j = 0; j < 32; ++j) acc[j] = 0.f;

  for (int c = 0; c < CC; ++c) {
    float xv = xb[(size_t)c * NNX + n];
#pragma unroll
    for (int j = 0; j < 32; ++j) acc[j] += Wv[(og * 32 + j) * CC + c] * xv;
  }

  float* vb = v + (size_t)b * CC * NNX;
#pragma unroll
  for (int j = 0; j < 32; ++j)
    vb[(size_t)(og * 32 + j) * NNX + n] = acc[j] + bv[og * 32 + j];
}

// ---------------------------------------------------------------------------
// Attention: per block, one batch b and 64 queries [m0, m0+64).
//   s[m,n] = sum_i q[b,i,m0+m] * k[b,i,n];  e = exp(s)  (no max-sub needed:
//   |s| <~ 35 so exp stays well inside fp32 range)
//   O[c,m] = sum_n e[m,n] * v[b,c,n];  l[m] = sum_n e[m,n]
//   out[b,c,m0+m] = gamma * O[c,m] / l[m] + x[b,c,m0+m]
// Roles: score phase: thread -> (sm = t&63, ncol = t>>6 covers 8 n's).
//        PV phase:    thread -> (mq = t&15 -> 4 m's, cg = t>>4 -> 16 c's).
// ---------------------------------------------------------------------------
__global__ __launch_bounds__(256) void attn_kernel(
    const float* __restrict__ q, const float* __restrict__ k,
    const float* __restrict__ v, const float* __restrict__ x,
    const float* __restrict__ gamma, float* __restrict__ out) {
  __shared__ __align__(16) float ks_[NT][KSTR];   // K tile, [n][i]
  __shared__ __align__(16) float es[NT][MT];      // exp(scores), [n][m]
  __shared__ __align__(16) float vs_[NT][VSTR];   // V tile, [n][c]
  __shared__ float lred[4][MT];
  __shared__ float lfin[MT];

  const int t  = threadIdx.x;
  const int b  = blockIdx.y;
  const int m0 = blockIdx.x * MT;

  const float* qb = q + (size_t)b * II * NNX;
  const float* kb = k + (size_t)b * II * NNX;
  const float* vb = v + (size_t)b * CC * NNX;

  // Score-phase role
  const int sm   = t & 63;
  const int ncol = t >> 6;  // == wave id (uniform per wave)

  // Q for this thread's query, loop-invariant: keep in registers.
  float qr[II];
#pragma unroll
  for (int i = 0; i < II; ++i) qr[i] = qb[(size_t)i * NNX + m0 + sm];

  // PV-phase role
  const int mq = t & 15;  // m = mq*4 + j, j in 0..3
  const int cg = t >> 4;  // c = cg*16 + jc, jc in 0..15

  float acc[16][4];  // [jc][j]
#pragma unroll
  for (int jc = 0; jc < 16; ++jc)
#pragma unroll
    for (int j = 0; j < 4; ++j) acc[jc][j] = 0.f;

  float lpart = 0.f;

  for (int n1 = 0; n1 < NNX; n1 += NT) {
    // Stage K tile: 32x32, coalesced global reads (n fastest)
#pragma unroll
    for (int r = 0; r < 4; ++r) {
      int idx = t + r * 256;
      int i  = idx >> 5;
      int nn = idx & 31;
      ks_[nn][i] = kb[(size_t)i * NNX + n1 + nn];
    }
    // Stage V tile: 32n x 256c, coalesced global reads (n fastest)
#pragma unroll
    for (int r = 0; r < 32; ++r) {
      int idx = t + r * 256;
      int c  = idx >> 5;
      int nn = idx & 31;
      vs_[nn][c] = vb[(size_t)c * NNX + n1 + nn];
    }
    __syncthreads();

    // Scores + exp: thread computes 8 scores for its query sm
#pragma unroll
    for (int iw = 0; iw < 8; ++iw) {
      int nn = ncol * 8 + iw;  // wave-uniform -> K reads broadcast
      float s = 0.f;
#pragma unroll
      for (int i4 = 0; i4 < 8; ++i4) {
        float4 kv = *(const float4*)&ks_[nn][i4 * 4];
        s += qr[i4 * 4 + 0] * kv.x + qr[i4 * 4 + 1] * kv.y +
             qr[i4 * 4 + 2] * kv.z + qr[i4 * 4 + 3] * kv.w;
      }
      float e = __expf(s);
      lpart += e;
      es[nn][sm] = e;
    }
    __syncthreads();

    // PV accumulate: per n, 5 b128 LDS reads feed 64 FMAs
#pragma unroll 4
    for (int nn = 0; nn < NT; ++nn) {
      float4 e4 = *(const float4*)&es[nn][mq * 4];
      float4 v0 = *(const float4*)&vs_[nn][cg * 16 + 0];
      float4 v1 = *(const float4*)&vs_[nn][cg * 16 + 4];
      float4 v2 = *(const float4*)&vs_[nn][cg * 16 + 8];
      float4 v3 = *(const float4*)&vs_[nn][cg * 16 + 12];
      float ev[4] = {e4.x, e4.y, e4.z, e4.w};
      float vv[16] = {v0.x, v0.y, v0.z, v0.w, v1.x, v1.y, v1.z, v1.w,
                      v2.x, v2.y, v2.z, v2.w, v3.x, v3.y, v3.z, v3.w};
#pragma unroll
      for (int jc = 0; jc < 16; ++jc)
#pragma unroll
        for (int j = 0; j < 4; ++j) acc[jc][j] += ev[j] * vv[jc];
    }
    __syncthreads();
  }

  // Reduce softmax denominator l[m] across the 4 waves
  lred[ncol][sm] = lpart;
  __syncthreads();
  if (t < 64) lfin[t] = lred[0][t] + lred[1][t] + lred[2][t] + lred[3][t];
  __syncthreads();

  const float g = gamma[0];
  float linv[4];
#pragma unroll
  for (int j = 0; j < 4; ++j) linv[j] = 1.0f / lfin[mq * 4 + j];

  const float* xb = x + (size_t)b * CC * NNX;
  float* ob       = out + (size_t)b * CC * NNX;
#pragma unroll
  for (int jc = 0; jc < 16; ++jc) {
    int c = cg * 16 + jc;
    size_t base = (size_t)c * NNX + m0 + mq * 4;
    float4 xv = *(const float4*)&xb[base];
    float4 o;
    o.x = g * acc[jc][0] * linv[0] + xv.x;
    o.y = g * acc[jc][1] * linv[1] + xv.y;
    o.z = g * acc[jc][2] * linv[2] + xv.z;
    o.w = g * acc[jc][3] * linv[3] + xv.w;
    *(float4*)&ob[base] = o;
  }
}

// ---------------------------------------------------------------------------
extern "C" void kernel_launch(void* const* d_in, const int* in_sizes, int n_in,
                              void* d_out, int out_size, void* d_ws, size_t ws_size,
                              hipStream_t stream) {
  const float* x     = (const float*)d_in[0];
  const float* Wq    = (const float*)d_in[1];
  const float* bq    = (const float*)d_in[2];
  const float* Wk    = (const float*)d_in[3];
  const float* bk    = (const float*)d_in[4];
  const float* Wv    = (const float*)d_in[5];
  const float* bv    = (const float*)d_in[6];
  const float* gamma = (const float*)d_in[7];
  float* out = (float*)d_out;

  // Workspace layout (floats): q [8*32*4096], k [8*32*4096], v [8*256*4096]
  float* ws = (float*)d_ws;
  float* q = ws;
  float* k = ws + (size_t)BB * II * NNX;
  float* v = ws + (size_t)2 * BB * II * NNX;

  dim3 gqk(NNX / 256, BB, 2);
  qk_proj<<<gqk, 256, 0, stream>>>(x, Wq, bq, Wk, bk, q, k);

  dim3 gv(NNX / 256, BB, 8);
  v_proj<<<gv, 256, 0, stream>>>(x, Wv, bv, v);

  dim3 ga(NNX / MT, BB);
  attn_kernel<<<ga, 256, 0, stream>>>(q, k, v, x, gamma, out);
}

// Round 2
// 527.489 us; speedup vs baseline: 2.7044x; 2.7044x over previous
//
#include <hip/hip_runtime.h>
#include <hip/hip_bf16.h>

// Problem: B=8, C=256, H=W=64 -> N=4096, inter=32. fp32 in/out.
#define BB 8
#define CC 256
#define NN 4096
#define II 32

typedef __bf16 bf16_t;
typedef bf16_t bf16x8 __attribute__((ext_vector_type(8)));
typedef float f32x4 __attribute__((ext_vector_type(4)));

// ---------------------------------------------------------------------------
// Fused q,k projection. Thread owns one n; computes all 32 q + 32 k channels.
// Output layout: q[b][n][i], i fastest (MFMA-frag-native) — 64B/thread,
// packed bf16x8 stores. x read ONCE.
// ---------------------------------------------------------------------------
__global__ __launch_bounds__(256) void qk_proj(
    const float* __restrict__ x,
    const float* __restrict__ Wq, const float* __restrict__ bq,
    const float* __restrict__ Wk, const float* __restrict__ bk,
    bf16_t* __restrict__ q, bf16_t* __restrict__ k) {
  const int n = blockIdx.x * 256 + threadIdx.x;
  const int b = blockIdx.y;
  const float* xb = x + (size_t)b * CC * NN;

  float aq[II], ak[II];
#pragma unroll
  for (int i = 0; i < II; ++i) { aq[i] = 0.f; ak[i] = 0.f; }

  for (int c = 0; c < CC; ++c) {
    float xv = xb[(size_t)c * NN + n];
#pragma unroll
    for (int i = 0; i < II; ++i) {
      aq[i] += Wq[i * CC + c] * xv;  // W loads are wave-uniform -> s_load
      ak[i] += Wk[i * CC + c] * xv;
    }
  }

  bf16_t* qo = q + ((size_t)b * NN + n) * II;
  bf16_t* ko = k + ((size_t)b * NN + n) * II;
  union { bf16_t h[8]; uint4 u; } pk;
#pragma unroll
  for (int g = 0; g < 4; ++g) {
#pragma unroll
    for (int j = 0; j < 8; ++j) pk.h[j] = (bf16_t)(aq[g * 8 + j] + bq[g * 8 + j]);
    *(uint4*)(qo + g * 8) = pk.u;
  }
#pragma unroll
  for (int g = 0; g < 4; ++g) {
#pragma unroll
    for (int j = 0; j < 8; ++j) pk.h[j] = (bf16_t)(ak[g * 8 + j] + bk[g * 8 + j]);
    *(uint4*)(ko + g * 8) = pk.u;
  }
}

// ---------------------------------------------------------------------------
// v projection. Thread owns one n, 64 output channels per z-group (x read 4x,
// not 8x). Output layout: v[b][c][n], n fastest (V A-frag native).
// ---------------------------------------------------------------------------
__global__ __launch_bounds__(256) void v_proj(
    const float* __restrict__ x,
    const float* __restrict__ Wv, const float* __restrict__ bv,
    bf16_t* __restrict__ v) {
  const int n  = blockIdx.x * 256 + threadIdx.x;
  const int b  = blockIdx.y;
  const int og = blockIdx.z;  // 64 output channels per group

  const float* xb = x + (size_t)b * CC * NN;
  float acc[64];
#pragma unroll
  for (int j = 0; j < 64; ++j) acc[j] = 0.f;

  for (int c = 0; c < CC; ++c) {
    float xv = xb[(size_t)c * NN + n];
#pragma unroll
    for (int j = 0; j < 64; ++j) acc[j] += Wv[(og * 64 + j) * CC + c] * xv;
  }

  bf16_t* vb = v + (size_t)b * CC * NN;
#pragma unroll
  for (int j = 0; j < 64; ++j)
    vb[(size_t)(og * 64 + j) * NN + n] = (bf16_t)(acc[j] + bv[og * 64 + j]);
}

// ---------------------------------------------------------------------------
// MFMA attention. Block: batch b, 64 queries [m0,m0+64). 4 waves; wave w owns
// c-range [w*64, w*64+64). N-loop in tiles of 64.
//   Phase 1: wave w computes S_T[n-sub w][all 64 m] = K·Q^T (4 mfma),
//            exp -> bf16 P written to LDS (XOR-swizzled 16B chunks).
//   Phase 2: O[c][m] += V·P^T: V A-frags b128 DIRECT FROM GLOBAL (L2-hot),
//            P B-frags b128 from LDS (conflict-free via swizzle).
// No max-subtraction: |s|<~35, exp fits fp32/bf16 range; partials add.
// ---------------------------------------------------------------------------
__global__ __launch_bounds__(256) void attn_mfma(
    const bf16_t* __restrict__ q, const bf16_t* __restrict__ k,
    const bf16_t* __restrict__ v, const float* __restrict__ x,
    const float* __restrict__ gamma, float* __restrict__ out) {
  __shared__ bf16_t Pld[64 * 64];   // 8 KB, row m (64 bf16 = 128B), chunk-swizzled
  __shared__ float lred[16][64];
  __shared__ float lfin[64];

  const int t  = threadIdx.x;
  const int w  = t >> 6;   // wave id = c-split
  const int l  = t & 63;
  const int lo = l & 15;
  const int q4 = l >> 4;
  const int b  = blockIdx.y;
  const int m0 = blockIdx.x * 64;

  const bf16_t* qb = q + (size_t)b * NN * II;
  const bf16_t* kb = k + (size_t)b * NN * II;
  const bf16_t* vb = v + (size_t)b * CC * NN;

  // Q B-frags, loop-invariant, in registers (16 VGPRs)
  bf16x8 qf[4];
#pragma unroll
  for (int mt = 0; mt < 4; ++mt)
    qf[mt] = *(const bf16x8*)(qb + (size_t)(m0 + mt * 16 + lo) * II + q4 * 8);

  f32x4 acc[4][4];  // [ct][mt]
#pragma unroll
  for (int ct = 0; ct < 4; ++ct)
#pragma unroll
    for (int mt = 0; mt < 4; ++mt) acc[ct][mt] = (f32x4){0.f, 0.f, 0.f, 0.f};
  float lp[4] = {0.f, 0.f, 0.f, 0.f};

  const int cbase = w * 64;
  const f32x4 zero = (f32x4){0.f, 0.f, 0.f, 0.f};

  for (int n1 = 0; n1 < NN; n1 += 64) {
    // ---- Phase 1: scores for n-sub w ----
    bf16x8 kf = *(const bf16x8*)(kb + (size_t)(n1 + w * 16 + lo) * II + q4 * 8);
#pragma unroll
    for (int mt = 0; mt < 4; ++mt) {
      f32x4 s = __builtin_amdgcn_mfma_f32_16x16x32_bf16(kf, qf[mt], zero, 0, 0, 0);
      float e0 = __expf(s[0]), e1 = __expf(s[1]), e2 = __expf(s[2]), e3 = __expf(s[3]);
      lp[mt] += (e0 + e1) + (e2 + e3);
      union { bf16_t h[4]; uint2 u2; } ph;
      ph.h[0] = (bf16_t)e0; ph.h[1] = (bf16_t)e1;
      ph.h[2] = (bf16_t)e2; ph.h[3] = (bf16_t)e3;
      // P[m][n_local], n_local = w*16 + q4*4 + r. Swizzle: 16B chunk c8 at
      // row m lives at phys chunk c8 ^ (m&7). Write = 8B half-chunk.
      int m_loc = mt * 16 + lo;
      int c8    = w * 2 + (q4 >> 1);
      int elem  = m_loc * 64 + ((c8 ^ (m_loc & 7)) * 8) + (q4 & 1) * 4;
      *(uint2*)&Pld[elem] = ph.u2;
    }
    __syncthreads();

    // ---- Phase 2: PV ----
#pragma unroll
    for (int kc = 0; kc < 2; ++kc) {
      bf16x8 pf[4];
#pragma unroll
      for (int mt = 0; mt < 4; ++mt) {
        int m_loc = mt * 16 + lo;
        int c8    = kc * 4 + q4;
        pf[mt] = *(const bf16x8*)&Pld[m_loc * 64 + ((c8 ^ (m_loc & 7)) * 8)];
      }
#pragma unroll
      for (int ct = 0; ct < 4; ++ct) {
        bf16x8 vf = *(const bf16x8*)(vb + (size_t)(cbase + ct * 16 + lo) * NN +
                                     n1 + kc * 32 + q4 * 8);
#pragma unroll
        for (int mt = 0; mt < 4; ++mt)
          acc[ct][mt] = __builtin_amdgcn_mfma_f32_16x16x32_bf16(vf, pf[mt],
                                                               acc[ct][mt], 0, 0, 0);
      }
    }
    __syncthreads();
  }

  // ---- softmax denominator reduction ----
#pragma unroll
  for (int mt = 0; mt < 4; ++mt) lred[w * 4 + q4][mt * 16 + lo] = lp[mt];
  __syncthreads();
  if (t < 64) {
    float s = 0.f;
#pragma unroll
    for (int j = 0; j < 16; ++j) s += lred[j][t];
    lfin[t] = s;
  }
  __syncthreads();

  const float g = gamma[0];
  float linv[4];
#pragma unroll
  for (int mt = 0; mt < 4; ++mt) linv[mt] = 1.0f / lfin[mt * 16 + lo];

  // ---- epilogue: out = gamma * O/l + x ----
#pragma unroll
  for (int ct = 0; ct < 4; ++ct) {
#pragma unroll
    for (int r = 0; r < 4; ++r) {
      int c = cbase + ct * 16 + q4 * 4 + r;
      const float* xrow = x + ((size_t)b * CC + c) * NN + m0;
      float* orow       = out + ((size_t)b * CC + c) * NN + m0;
#pragma unroll
      for (int mt = 0; mt < 4; ++mt) {
        int m = mt * 16 + lo;
        orow[m] = g * acc[ct][mt][r] * linv[mt] + xrow[m];
      }
    }
  }
}

// ---------------------------------------------------------------------------
extern "C" void kernel_launch(void* const* d_in, const int* in_sizes, int n_in,
                              void* d_out, int out_size, void* d_ws, size_t ws_size,
                              hipStream_t stream) {
  const float* x     = (const float*)d_in[0];
  const float* Wq    = (const float*)d_in[1];
  const float* bq    = (const float*)d_in[2];
  const float* Wk    = (const float*)d_in[3];
  const float* bk    = (const float*)d_in[4];
  const float* Wv    = (const float*)d_in[5];
  const float* bv    = (const float*)d_in[6];
  const float* gamma = (const float*)d_in[7];
  float* out = (float*)d_out;

  // Workspace (bf16): q [8*4096*32] (2MB), k same, v [8*256*4096] (16MB)
  bf16_t* ws = (bf16_t*)d_ws;
  bf16_t* q = ws;
  bf16_t* k = ws + (size_t)BB * NN * II;
  bf16_t* v = ws + (size_t)2 * BB * NN * II;

  dim3 gqk(NN / 256, BB);
  qk_proj<<<gqk, 256, 0, stream>>>(x, Wq, bq, Wk, bk, q, k);

  dim3 gv(NN / 256, BB, 4);
  v_proj<<<gv, 256, 0, stream>>>(x, Wv, bv, v);

  dim3 ga(NN / 64, BB);
  attn_mfma<<<ga, 256, 0, stream>>>(q, k, v, x, gamma, out);
}

// Round 3
// 271.404 us; speedup vs baseline: 5.2562x; 1.9436x over previous
//
#include <hip/hip_runtime.h>
#include <hip/hip_bf16.h>

// Problem: B=8, C=256, H=W=64 -> N=4096, inter=32. fp32 in/out.
#define BB 8
#define CC 256
#define NN 4096
#define II 32

typedef __bf16 bf16_t;
typedef bf16_t bf16x8 __attribute__((ext_vector_type(8)));
typedef float f32x4 __attribute__((ext_vector_type(4)));

// ---------------------------------------------------------------------------
// Weight pre-convert: Wb[320][256] bf16 = [Wq(32); Wk(32); Wv(256)] rows.
// ---------------------------------------------------------------------------
__global__ __launch_bounds__(256) void wconv(
    const float* __restrict__ Wq, const float* __restrict__ Wk,
    const float* __restrict__ Wv, bf16_t* __restrict__ Wb) {
  int idx = blockIdx.x * 256 + threadIdx.x;  // < 320*256
  int o = idx >> 8, c = idx & 255;
  float w = (o < 32) ? Wq[o * 256 + c]
          : (o < 64) ? Wk[(o - 32) * 256 + c]
                     : Wv[(o - 64) * 256 + c];
  Wb[idx] = (bf16_t)w;
}

// ---------------------------------------------------------------------------
// Fused q/k/v projection as MFMA GEMM, no LDS.
//   out[o, n] = sum_c W[o,c] * x[b,c,n]   (o in 320 = 20 o-tiles of 16)
// A = x^T (m = pixel n, k = c): frags loaded DIRECT from global fp32
//   (8 stride-N dwords per lane), converted to bf16 in-register.
// B = Wb (k = c, nB = o): b128 bf16 frags, identical across blocks -> L2.
// D: col(lane&15) = o, row(q4*4+r) = n.
// Grid (16 n-blocks, 4 o-groups of 5 tiles, 8 batches); 4 waves x 64 n.
// Epilogue routes each o-tile: q,k -> [b][n][32] bf16; v -> [b][c][n] bf16.
// ---------------------------------------------------------------------------
__global__ __launch_bounds__(256) void qkv_proj(
    const float* __restrict__ x, const bf16_t* __restrict__ Wb,
    const float* __restrict__ bq, const float* __restrict__ bk,
    const float* __restrict__ bv,
    bf16_t* __restrict__ q, bf16_t* __restrict__ k, bf16_t* __restrict__ v) {
  const int t  = threadIdx.x;
  const int w  = t >> 6;
  const int l  = t & 63;
  const int lo = l & 15;
  const int q4 = l >> 4;
  const int og = blockIdx.y;  // o-tile group: tiles [og*5, og*5+5)
  const int b  = blockIdx.z;
  const int nbase = blockIdx.x * 256 + w * 64;

  const float* xb = x + (size_t)b * CC * NN;

  f32x4 acc[5][4];  // [o-tile][n-subtile]
#pragma unroll
  for (int ot = 0; ot < 5; ++ot)
#pragma unroll
    for (int ms = 0; ms < 4; ++ms) acc[ot][ms] = (f32x4){0.f, 0.f, 0.f, 0.f};

  for (int ks = 0; ks < 8; ++ks) {
    const int c0 = ks * 32 + q4 * 8;
    bf16x8 bw[5];
#pragma unroll
    for (int ot = 0; ot < 5; ++ot)
      bw[ot] = *(const bf16x8*)&Wb[((og * 5 + ot) * 16 + lo) * 256 + c0];
#pragma unroll
    for (int ms = 0; ms < 4; ++ms) {
      const float* xp = xb + (size_t)c0 * NN + nbase + ms * 16 + lo;
      union { bf16_t h[8]; bf16x8 v8; } af;
#pragma unroll
      for (int j = 0; j < 8; ++j) af.h[j] = (bf16_t)xp[(size_t)j * NN];
#pragma unroll
      for (int ot = 0; ot < 5; ++ot)
        acc[ot][ms] = __builtin_amdgcn_mfma_f32_16x16x32_bf16(
            af.v8, bw[ot], acc[ot][ms], 0, 0, 0);
    }
  }

  // Epilogue
#pragma unroll
  for (int ot = 0; ot < 5; ++ot) {
    const int gt = og * 5 + ot;  // global o-tile
    if (gt < 4) {
      // q (gt 0,1) or k (gt 2,3): channel i, scatter 2B stores [b][n][i]
      const bool isq = gt < 2;
      const int i = (gt & 1) * 16 + lo;
      const float bias = isq ? bq[i] : bk[i];
      bf16_t* dst = (isq ? q : k) + (size_t)b * NN * II;
#pragma unroll
      for (int ms = 0; ms < 4; ++ms) {
#pragma unroll
        for (int r = 0; r < 4; ++r) {
          int n = nbase + ms * 16 + q4 * 4 + r;
          dst[(size_t)n * II + i] = (bf16_t)(acc[ot][ms][r] + bias);
        }
      }
    } else {
      const int cv = (gt - 4) * 16 + lo;
      const float bias = bv[cv];
      bf16_t* dst = v + ((size_t)b * CC + cv) * NN;
#pragma unroll
      for (int ms = 0; ms < 4; ++ms) {
        union { bf16_t h[4]; uint2 u; } pk;
#pragma unroll
        for (int r = 0; r < 4; ++r) pk.h[r] = (bf16_t)(acc[ot][ms][r] + bias);
        *(uint2*)&dst[nbase + ms * 16 + q4 * 4] = pk.u;
      }
    }
  }
}

// ---------------------------------------------------------------------------
// MFMA attention (unchanged from R2). Block: batch b, 64 queries [m0,m0+64).
// 4 waves; wave w owns c-range [w*64, w*64+64). N-loop in tiles of 64.
//   Phase 1: wave w computes S_T[n-sub w][all 64 m] = K·Q^T (4 mfma),
//            exp -> bf16 P written to LDS (XOR-swizzled 16B chunks).
//   Phase 2: O[c][m] += V·P^T: V A-frags b128 DIRECT FROM GLOBAL (L2-hot),
//            P B-frags b128 from LDS (conflict-free via swizzle).
// No max-subtraction: |s|<~35, exp fits fp32/bf16 range; partials add.
// ---------------------------------------------------------------------------
__global__ __launch_bounds__(256) void attn_mfma(
    const bf16_t* __restrict__ q, const bf16_t* __restrict__ k,
    const bf16_t* __restrict__ v, const float* __restrict__ x,
    const float* __restrict__ gamma, float* __restrict__ out) {
  __shared__ bf16_t Pld[64 * 64];   // 8 KB, row m (64 bf16 = 128B), chunk-swizzled
  __shared__ float lred[16][64];
  __shared__ float lfin[64];

  const int t  = threadIdx.x;
  const int w  = t >> 6;   // wave id = c-split
  const int l  = t & 63;
  const int lo = l & 15;
  const int q4 = l >> 4;
  const int b  = blockIdx.y;
  const int m0 = blockIdx.x * 64;

  const bf16_t* qb = q + (size_t)b * NN * II;
  const bf16_t* kb = k + (size_t)b * NN * II;
  const bf16_t* vb = v + (size_t)b * CC * NN;

  // Q B-frags, loop-invariant, in registers (16 VGPRs)
  bf16x8 qf[4];
#pragma unroll
  for (int mt = 0; mt < 4; ++mt)
    qf[mt] = *(const bf16x8*)(qb + (size_t)(m0 + mt * 16 + lo) * II + q4 * 8);

  f32x4 acc[4][4];  // [ct][mt]
#pragma unroll
  for (int ct = 0; ct < 4; ++ct)
#pragma unroll
    for (int mt = 0; mt < 4; ++mt) acc[ct][mt] = (f32x4){0.f, 0.f, 0.f, 0.f};
  float lp[4] = {0.f, 0.f, 0.f, 0.f};

  const int cbase = w * 64;
  const f32x4 zero = (f32x4){0.f, 0.f, 0.f, 0.f};

  for (int n1 = 0; n1 < NN; n1 += 64) {
    // ---- Phase 1: scores for n-sub w ----
    bf16x8 kf = *(const bf16x8*)(kb + (size_t)(n1 + w * 16 + lo) * II + q4 * 8);
#pragma unroll
    for (int mt = 0; mt < 4; ++mt) {
      f32x4 s = __builtin_amdgcn_mfma_f32_16x16x32_bf16(kf, qf[mt], zero, 0, 0, 0);
      float e0 = __expf(s[0]), e1 = __expf(s[1]), e2 = __expf(s[2]), e3 = __expf(s[3]);
      lp[mt] += (e0 + e1) + (e2 + e3);
      union { bf16_t h[4]; uint2 u2; } ph;
      ph.h[0] = (bf16_t)e0; ph.h[1] = (bf16_t)e1;
      ph.h[2] = (bf16_t)e2; ph.h[3] = (bf16_t)e3;
      // P[m][n_local], n_local = w*16 + q4*4 + r. Swizzle: 16B chunk c8 at
      // row m lives at phys chunk c8 ^ (m&7). Write = 8B half-chunk.
      int m_loc = mt * 16 + lo;
      int c8    = w * 2 + (q4 >> 1);
      int elem  = m_loc * 64 + ((c8 ^ (m_loc & 7)) * 8) + (q4 & 1) * 4;
      *(uint2*)&Pld[elem] = ph.u2;
    }
    __syncthreads();

    // ---- Phase 2: PV ----
#pragma unroll
    for (int kc = 0; kc < 2; ++kc) {
      bf16x8 pf[4];
#pragma unroll
      for (int mt = 0; mt < 4; ++mt) {
        int m_loc = mt * 16 + lo;
        int c8    = kc * 4 + q4;
        pf[mt] = *(const bf16x8*)&Pld[m_loc * 64 + ((c8 ^ (m_loc & 7)) * 8)];
      }
#pragma unroll
      for (int ct = 0; ct < 4; ++ct) {
        bf16x8 vf = *(const bf16x8*)(vb + (size_t)(cbase + ct * 16 + lo) * NN +
                                     n1 + kc * 32 + q4 * 8);
#pragma unroll
        for (int mt = 0; mt < 4; ++mt)
          acc[ct][mt] = __builtin_amdgcn_mfma_f32_16x16x32_bf16(vf, pf[mt],
                                                               acc[ct][mt], 0, 0, 0);
      }
    }
    __syncthreads();
  }

  // ---- softmax denominator reduction ----
#pragma unroll
  for (int mt = 0; mt < 4; ++mt) lred[w * 4 + q4][mt * 16 + lo] = lp[mt];
  __syncthreads();
  if (t < 64) {
    float s = 0.f;
#pragma unroll
    for (int j = 0; j < 16; ++j) s += lred[j][t];
    lfin[t] = s;
  }
  __syncthreads();

  const float g = gamma[0];
  float linv[4];
#pragma unroll
  for (int mt = 0; mt < 4; ++mt) linv[mt] = 1.0f / lfin[mt * 16 + lo];

  // ---- epilogue: out = gamma * O/l + x ----
#pragma unroll
  for (int ct = 0; ct < 4; ++ct) {
#pragma unroll
    for (int r = 0; r < 4; ++r) {
      int c = cbase + ct * 16 + q4 * 4 + r;
      const float* xrow = x + ((size_t)b * CC + c) * NN + m0;
      float* orow       = out + ((size_t)b * CC + c) * NN + m0;
#pragma unroll
      for (int mt = 0; mt < 4; ++mt) {
        int m = mt * 16 + lo;
        orow[m] = g * acc[ct][mt][r] * linv[mt] + xrow[m];
      }
    }
  }
}

// ---------------------------------------------------------------------------
extern "C" void kernel_launch(void* const* d_in, const int* in_sizes, int n_in,
                              void* d_out, int out_size, void* d_ws, size_t ws_size,
                              hipStream_t stream) {
  const float* x     = (const float*)d_in[0];
  const float* Wq    = (const float*)d_in[1];
  const float* bq    = (const float*)d_in[2];
  const float* Wk    = (const float*)d_in[3];
  const float* bk    = (const float*)d_in[4];
  const float* Wv    = (const float*)d_in[5];
  const float* bv    = (const float*)d_in[6];
  const float* gamma = (const float*)d_in[7];
  float* out = (float*)d_out;

  // Workspace (bf16): q 2MB, k 2MB, v 16MB, Wb 160KB
  bf16_t* ws = (bf16_t*)d_ws;
  bf16_t* q  = ws;
  bf16_t* k  = q + (size_t)BB * NN * II;
  bf16_t* v  = k + (size_t)BB * NN * II;
  bf16_t* Wb = v + (size_t)BB * CC * NN;

  wconv<<<dim3(320), 256, 0, stream>>>(Wq, Wk, Wv, Wb);

  dim3 gp(NN / 256, 4, BB);
  qkv_proj<<<gp, 256, 0, stream>>>(x, Wb, bq, bk, bv, q, k, v);

  dim3 ga(NN / 64, BB);
  attn_mfma<<<ga, 256, 0, stream>>>(q, k, v, x, gamma, out);
}

// Round 4
// 255.994 us; speedup vs baseline: 5.5726x; 1.0602x over previous
//
#include <hip/hip_runtime.h>
#include <hip/hip_bf16.h>

// Problem: B=8, C=256, H=W=64 -> N=4096, inter=32. fp32 in/out.
#define BB 8
#define CC 256
#define NN 4096
#define II 32

typedef __bf16 bf16_t;
typedef bf16_t bf16x8 __attribute__((ext_vector_type(8)));
typedef float f32x4 __attribute__((ext_vector_type(4)));

// ---------------------------------------------------------------------------
// Weight pre-convert: Wb[320][256] bf16 = [Wq(32); Wk(32); Wv(256)] rows.
// ---------------------------------------------------------------------------
__global__ __launch_bounds__(256) void wconv(
    const float* __restrict__ Wq, const float* __restrict__ Wk,
    const float* __restrict__ Wv, bf16_t* __restrict__ Wb) {
  int idx = blockIdx.x * 256 + threadIdx.x;  // < 320*256
  int o = idx >> 8, c = idx & 255;
  float w = (o < 32) ? Wq[o * 256 + c]
          : (o < 64) ? Wk[(o - 32) * 256 + c]
                     : Wv[(o - 64) * 256 + c];
  Wb[idx] = (bf16_t)w;
}

// ---------------------------------------------------------------------------
// x transpose+convert: xt[b][n][c] bf16 from x[b][c][n] fp32.
// 64c x 64n tiles through LDS; coalesced float4 reads, uint2 writes.
// Makes proj A-frags single b128 loads (k=c contiguous per pixel).
// ---------------------------------------------------------------------------
__global__ __launch_bounds__(256) void xcvt(
    const float* __restrict__ x, bf16_t* __restrict__ xt) {
  __shared__ bf16_t tl[64][72];  // [n][c], padded
  const int t  = threadIdx.x;
  const int n0 = blockIdx.x * 64, c0 = blockIdx.y * 64, b = blockIdx.z;

  const float* xb = x + ((size_t)b * CC + c0) * NN + n0;
#pragma unroll
  for (int p = 0; p < 4; ++p) {
    int cl = (t >> 4) + 16 * p;
    int nl = (t & 15) * 4;
    float4 v = *(const float4*)&xb[(size_t)cl * NN + nl];
    tl[nl + 0][cl] = (bf16_t)v.x;
    tl[nl + 1][cl] = (bf16_t)v.y;
    tl[nl + 2][cl] = (bf16_t)v.z;
    tl[nl + 3][cl] = (bf16_t)v.w;
  }
  __syncthreads();
  bf16_t* xtb = xt + ((size_t)b * NN + n0) * CC + c0;
#pragma unroll
  for (int p = 0; p < 4; ++p) {
    int nl = (t >> 4) + 16 * p;
    int cl = (t & 15) * 4;
    union { bf16_t h[4]; uint2 u; } pk;
    pk.h[0] = tl[nl][cl + 0]; pk.h[1] = tl[nl][cl + 1];
    pk.h[2] = tl[nl][cl + 2]; pk.h[3] = tl[nl][cl + 3];
    *(uint2*)&xtb[(size_t)nl * CC + cl] = pk.u;
  }
}

// ---------------------------------------------------------------------------
// Fused q/k/v projection as MFMA GEMM, no LDS, all-b128 loads.
//   out[o, n] = sum_c W[o,c] * xt[b,n,c]   (o in 320 = 20 o-tiles of 16)
// A = xt (m = n, k = c contiguous): b128 frags DIRECT from global.
// B = Wb: b128 frags, L2-broadcast across blocks.
// Grid (32 n-blocks, 4 o-groups of 5 tiles, 8 batches); 4 waves x 32 n.
// __launch_bounds__(256,4): cap VGPR 128 -> 4 blocks/CU for latency hiding.
// ---------------------------------------------------------------------------
__global__ __launch_bounds__(256, 4) void qkv_proj(
    const bf16_t* __restrict__ xt, const bf16_t* __restrict__ Wb,
    const float* __restrict__ bq, const float* __restrict__ bk,
    const float* __restrict__ bv,
    bf16_t* __restrict__ q, bf16_t* __restrict__ k, bf16_t* __restrict__ v) {
  const int t  = threadIdx.x;
  const int w  = t >> 6;
  const int l  = t & 63;
  const int lo = l & 15;
  const int q4 = l >> 4;
  const int og = blockIdx.y;  // o-tile group: tiles [og*5, og*5+5)
  const int b  = blockIdx.z;
  const int nbase = blockIdx.x * 128 + w * 32;

  const bf16_t* xb = xt + (size_t)b * NN * CC;

  f32x4 acc[5][2];  // [o-tile][n-subtile]
#pragma unroll
  for (int ot = 0; ot < 5; ++ot)
#pragma unroll
    for (int ms = 0; ms < 2; ++ms) acc[ot][ms] = (f32x4){0.f, 0.f, 0.f, 0.f};

#pragma unroll 2
  for (int ks = 0; ks < 8; ++ks) {
    const int c0 = ks * 32 + q4 * 8;
    bf16x8 af[2];
#pragma unroll
    for (int ms = 0; ms < 2; ++ms)
      af[ms] = *(const bf16x8*)&xb[(size_t)(nbase + ms * 16 + lo) * CC + c0];
    bf16x8 bw[5];
#pragma unroll
    for (int ot = 0; ot < 5; ++ot)
      bw[ot] = *(const bf16x8*)&Wb[((og * 5 + ot) * 16 + lo) * 256 + c0];
#pragma unroll
    for (int ms = 0; ms < 2; ++ms)
#pragma unroll
      for (int ot = 0; ot < 5; ++ot)
        acc[ot][ms] = __builtin_amdgcn_mfma_f32_16x16x32_bf16(
            af[ms], bw[ot], acc[ot][ms], 0, 0, 0);
  }

  // Epilogue: q,k -> [b][n][32] bf16 (2B scatter); v -> [b][c][n] bf16.
#pragma unroll
  for (int ot = 0; ot < 5; ++ot) {
    const int gt = og * 5 + ot;  // global o-tile
    if (gt < 4) {
      const bool isq = gt < 2;
      const int i = (gt & 1) * 16 + lo;
      const float bias = isq ? bq[i] : bk[i];
      bf16_t* dst = (isq ? q : k) + (size_t)b * NN * II;
#pragma unroll
      for (int ms = 0; ms < 2; ++ms) {
#pragma unroll
        for (int r = 0; r < 4; ++r) {
          int n = nbase + ms * 16 + q4 * 4 + r;
          dst[(size_t)n * II + i] = (bf16_t)(acc[ot][ms][r] + bias);
        }
      }
    } else {
      const int cv = (gt - 4) * 16 + lo;
      const float bias = bv[cv];
      bf16_t* dst = v + ((size_t)b * CC + cv) * NN;
#pragma unroll
      for (int ms = 0; ms < 2; ++ms) {
        union { bf16_t h[4]; uint2 u; } pk;
#pragma unroll
        for (int r = 0; r < 4; ++r) pk.h[r] = (bf16_t)(acc[ot][ms][r] + bias);
        *(uint2*)&dst[nbase + ms * 16 + q4 * 4] = pk.u;
      }
    }
  }
}

// ---------------------------------------------------------------------------
// MFMA attention, pipelined. Block: batch b, 64 queries [m0,m0+64). 4 waves;
// wave w owns c-range [w*64, w*64+64). N-loop in tiles of 64.
//   Top of iter: issue ALL 8 V-frag b128 global loads (needed in phase 2)
//   and next iter's K-frag load -> latency hides behind phase 1 + barrier.
//   Phase 1: S_T[n-sub w][all m] = K.Q^T (4 mfma), exp -> bf16 P to LDS
//            (double-buffered, XOR-swizzled chunks).
//   ONE __syncthreads per iter (double buffer makes write->read safe).
//   Phase 2: O[c][m] += V.P^T (32 mfma), P B-frags b128 from LDS.
// No max-subtraction: |s|<~35, exp fits fp32/bf16 range; partials add.
// ---------------------------------------------------------------------------
__global__ __launch_bounds__(256, 2) void attn_mfma(
    const bf16_t* __restrict__ q, const bf16_t* __restrict__ k,
    const bf16_t* __restrict__ v, const float* __restrict__ x,
    const float* __restrict__ gamma, float* __restrict__ out) {
  __shared__ bf16_t Pld[2][64 * 64];  // 16 KB double-buffered P
  __shared__ float lred[16][64];
  __shared__ float lfin[64];

  const int t  = threadIdx.x;
  const int w  = t >> 6;   // wave id = c-split
  const int l  = t & 63;
  const int lo = l & 15;
  const int q4 = l >> 4;
  const int b  = blockIdx.y;
  const int m0 = blockIdx.x * 64;

  const bf16_t* qb = q + (size_t)b * NN * II;
  const bf16_t* kb = k + (size_t)b * NN * II;
  const bf16_t* vb = v + (size_t)b * CC * NN;

  // Q B-frags, loop-invariant, in registers
  bf16x8 qf[4];
#pragma unroll
  for (int mt = 0; mt < 4; ++mt)
    qf[mt] = *(const bf16x8*)(qb + (size_t)(m0 + mt * 16 + lo) * II + q4 * 8);

  f32x4 acc[4][4];  // [ct][mt]
#pragma unroll
  for (int ct = 0; ct < 4; ++ct)
#pragma unroll
    for (int mt = 0; mt < 4; ++mt) acc[ct][mt] = (f32x4){0.f, 0.f, 0.f, 0.f};
  float lp[4] = {0.f, 0.f, 0.f, 0.f};

  const int cbase = w * 64;
  const f32x4 zero = (f32x4){0.f, 0.f, 0.f, 0.f};

  // Prime K frag for n1 = 0
  bf16x8 kf = *(const bf16x8*)(kb + (size_t)(w * 16 + lo) * II + q4 * 8);

  for (int n1 = 0, it = 0; n1 < NN; n1 += 64, ++it) {
    // ---- issue V frags for THIS iter + K frag for NEXT iter up front ----
    bf16x8 vf[8];
#pragma unroll
    for (int kc = 0; kc < 2; ++kc)
#pragma unroll
      for (int ct = 0; ct < 4; ++ct)
        vf[kc * 4 + ct] = *(const bf16x8*)(vb +
            (size_t)(cbase + ct * 16 + lo) * NN + n1 + kc * 32 + q4 * 8);
    const int n_next = (n1 + 64) & (NN - 1);  // wraps to 0 on last iter (discarded)
    bf16x8 kf_next = *(const bf16x8*)(kb + (size_t)(n_next + w * 16 + lo) * II + q4 * 8);

    // ---- Phase 1: scores for n-sub w ----
    bf16_t* Pb = Pld[it & 1];
#pragma unroll
    for (int mt = 0; mt < 4; ++mt) {
      f32x4 s = __builtin_amdgcn_mfma_f32_16x16x32_bf16(kf, qf[mt], zero, 0, 0, 0);
      float e0 = __expf(s[0]), e1 = __expf(s[1]), e2 = __expf(s[2]), e3 = __expf(s[3]);
      lp[mt] += (e0 + e1) + (e2 + e3);
      union { bf16_t h[4]; uint2 u2; } ph;
      ph.h[0] = (bf16_t)e0; ph.h[1] = (bf16_t)e1;
      ph.h[2] = (bf16_t)e2; ph.h[3] = (bf16_t)e3;
      // P[m][n_local], n_local = w*16 + q4*4 + r. 16B chunk c8 at row m
      // lives at phys chunk c8 ^ (m&7). Write = 8B half-chunk.
      int m_loc = mt * 16 + lo;
      int c8    = w * 2 + (q4 >> 1);
      int elem  = m_loc * 64 + ((c8 ^ (m_loc & 7)) * 8) + (q4 & 1) * 4;
      *(uint2*)&Pb[elem] = ph.u2;
    }
    __syncthreads();

    // ---- Phase 2: PV ----
#pragma unroll
    for (int kc = 0; kc < 2; ++kc) {
      bf16x8 pf[4];
#pragma unroll
      for (int mt = 0; mt < 4; ++mt) {
        int m_loc = mt * 16 + lo;
        int c8    = kc * 4 + q4;
        pf[mt] = *(const bf16x8*)&Pb[m_loc * 64 + ((c8 ^ (m_loc & 7)) * 8)];
      }
#pragma unroll
      for (int ct = 0; ct < 4; ++ct)
#pragma unroll
        for (int mt = 0; mt < 4; ++mt)
          acc[ct][mt] = __builtin_amdgcn_mfma_f32_16x16x32_bf16(
              vf[kc * 4 + ct], pf[mt], acc[ct][mt], 0, 0, 0);
    }
    kf = kf_next;
  }

  // ---- softmax denominator reduction ----
#pragma unroll
  for (int mt = 0; mt < 4; ++mt) lred[w * 4 + q4][mt * 16 + lo] = lp[mt];
  __syncthreads();
  if (t < 64) {
    float s = 0.f;
#pragma unroll
    for (int j = 0; j < 16; ++j) s += lred[j][t];
    lfin[t] = s;
  }
  __syncthreads();

  const float g = gamma[0];
  float linv[4];
#pragma unroll
  for (int mt = 0; mt < 4; ++mt) linv[mt] = 1.0f / lfin[mt * 16 + lo];

  // ---- epilogue: out = gamma * O/l + x ----
#pragma unroll
  for (int ct = 0; ct < 4; ++ct) {
#pragma unroll
    for (int r = 0; r < 4; ++r) {
      int c = cbase + ct * 16 + q4 * 4 + r;
      const float* xrow = x + ((size_t)b * CC + c) * NN + m0;
      float* orow       = out + ((size_t)b * CC + c) * NN + m0;
#pragma unroll
      for (int mt = 0; mt < 4; ++mt) {
        int m = mt * 16 + lo;
        orow[m] = g * acc[ct][mt][r] * linv[mt] + xrow[m];
      }
    }
  }
}

// ---------------------------------------------------------------------------
extern "C" void kernel_launch(void* const* d_in, const int* in_sizes, int n_in,
                              void* d_out, int out_size, void* d_ws, size_t ws_size,
                              hipStream_t stream) {
  const float* x     = (const float*)d_in[0];
  const float* Wq    = (const float*)d_in[1];
  const float* bq    = (const float*)d_in[2];
  const float* Wk    = (const float*)d_in[3];
  const float* bk    = (const float*)d_in[4];
  const float* Wv    = (const float*)d_in[5];
  const float* bv    = (const float*)d_in[6];
  const float* gamma = (const float*)d_in[7];
  float* out = (float*)d_out;

  // Workspace (bf16): q 2MB, k 2MB, v 16MB, Wb 160KB, xt 16MB (~36.2MB)
  bf16_t* ws = (bf16_t*)d_ws;
  bf16_t* q  = ws;
  bf16_t* k  = q + (size_t)BB * NN * II;
  bf16_t* v  = k + (size_t)BB * NN * II;
  bf16_t* Wb = v + (size_t)BB * CC * NN;
  bf16_t* xt = Wb + (size_t)320 * 256;

  wconv<<<dim3(320), 256, 0, stream>>>(Wq, Wk, Wv, Wb);

  dim3 gx(NN / 64, CC / 64, BB);
  xcvt<<<gx, 256, 0, stream>>>(x, xt);

  dim3 gp(NN / 128, 4, BB);
  qkv_proj<<<gp, 256, 0, stream>>>(xt, Wb, bq, bk, bv, q, k, v);

  dim3 ga(NN / 64, BB);
  attn_mfma<<<ga, 256, 0, stream>>>(q, k, v, x, gamma, out);
}